// Round 1
// 273.777 us; speedup vs baseline: 1.0431x; 1.0431x over previous
//
#include <hip/hip_runtime.h>
#include <hip/hip_bf16.h>
#include <math.h>

typedef float  f32x4  __attribute__((ext_vector_type(4)));
typedef short  bf16x4 __attribute__((ext_vector_type(4)));
typedef __bf16 bfv4   __attribute__((ext_vector_type(4)));

#define B_    16
#define S_    4096
#define D_    256
#define CK_   16                 // chunk length
#define NC_   (S_ / CK_)         // 256 chunks
#define NP_   (NC_ / 2)          // 128 fused pairs (32-row superchunks)
#define PBLOB_ 1664              // 512 Ta + 512 Tb + 512 Gx (bf16) + 64 ca + 64 cb (f32)
#define W_    8                  // waves per main block (column split)

// ---------------- helpers
__device__ __forceinline__ f32x4 mfma_bf16(bf16x4 a, bf16x4 b, f32x4 c) {
#if defined(__has_builtin) && __has_builtin(__builtin_amdgcn_mfma_f32_16x16x16bf16_1k)
    return __builtin_amdgcn_mfma_f32_16x16x16bf16_1k(a, b, c, 0, 0, 0);
#else
    f32x4 d;
    asm("v_mfma_f32_16x16x16_bf16 %0, %1, %2, %3" : "=v"(d) : "v"(a), "v"(b), "v"(c));
    return d;
#endif
}
__device__ __forceinline__ bf16x4 pk4(f32x4 v) {
    bfv4 h;
    h[0] = (__bf16)v[0]; h[1] = (__bf16)v[1]; h[2] = (__bf16)v[2]; h[3] = (__bf16)v[3];
    return __builtin_bit_cast(bf16x4, h);
}
__device__ __forceinline__ f32x4 up4(bf16x4 h) {
    f32x4 r;
    r[0] = __uint_as_float(((unsigned)(unsigned short)h[0]) << 16);
    r[1] = __uint_as_float(((unsigned)(unsigned short)h[1]) << 16);
    r[2] = __uint_as_float(((unsigned)(unsigned short)h[2]) << 16);
    r[3] = __uint_as_float(((unsigned)(unsigned short)h[3]) << 16);
    return r;
}

// ---------------- prepass: one 64-thread wave per (b, pair).
// Computes G_a = X_a X_a^T, G_b = X_b X_b^T, Gx = X_b X_a^T (all fp32-grade via
// hi/lo bf16 split MFMAs), then coeffs + T fwd-sub for BOTH chunks in parallel
// (32 lanes). Blob per pair: Ta | Tb | Gx (bf16, A-frag layout) | ca | cb (f32).
__global__ __launch_bounds__(64) void ldm_prep(
    const float* __restrict__ x,
    const float* __restrict__ eta_raw,
    const float* __restrict__ alpha_raw,
    unsigned char* __restrict__ blob)
{
    const int lane = threadIdx.x;
    const int b = blockIdx.x >> 7;            // NP_ = 128
    const int p = blockIdx.x & (NP_ - 1);
    const int l15 = lane & 15;
    const int q   = lane >> 4;

    __shared__ float Ga[256], Gb[256], Gxs[256];
    __shared__ float csh[32];
    __shared__ float Ts[2][256];

    // A-fragments: lane holds row t=l15, cols kb*16 + q*4 + {0..3}
    const float* xa = x + ((size_t)b * S_ + (size_t)p * 32 + l15) * D_ + q * 4;
    const float* xc = xa + 16 * D_;           // chunk b rows

    const f32x4 z = {0,0,0,0};
    f32x4 ga1=z, ga2=z, ga3=z, gb1=z, gb2=z, gb3=z, gx1=z, gx2=z, gx3=z;
    #pragma unroll 4
    for (int kb = 0; kb < 16; ++kb) {
        f32x4 va = *(const f32x4*)(xa + kb * 16);
        f32x4 vb = *(const f32x4*)(xc + kb * 16);
        bf16x4 ha = pk4(va), la = pk4(va - up4(ha));
        bf16x4 hb = pk4(vb), lb = pk4(vb - up4(hb));
        ga1 = mfma_bf16(ha, ha, ga1);
        ga2 = mfma_bf16(ha, la, ga2);
        ga3 = mfma_bf16(la, ha, ga3);
        gb1 = mfma_bf16(hb, hb, gb1);
        gb2 = mfma_bf16(hb, lb, gb2);
        gb3 = mfma_bf16(lb, hb, gb3);
        gx1 = mfma_bf16(hb, ha, gx1);         // Gx[t_b][t_a] = x_b . x_a
        gx2 = mfma_bf16(hb, la, gx2);
        gx3 = mfma_bf16(lb, ha, gx3);
    }
    f32x4 ga = (ga1 + ga2) + ga3;             // C layout: lane holds G[q*4+r][l15]
    f32x4 gb = (gb1 + gb2) + gb3;
    f32x4 gx = (gx1 + gx2) + gx3;
    // symmetric: transposed store = same matrix, contiguous b128 per lane
    *(f32x4*)(&Ga[l15 * 16 + q * 4]) = ga;
    *(f32x4*)(&Gb[l15 * 16 + q * 4]) = gb;
    // Gx not symmetric: true transpose via scatter -> Gxs[t_b*16 + t_a]
    #pragma unroll
    for (int r = 0; r < 4; ++r) Gxs[(q * 4 + r) * 16 + l15] = gx[r];
    __syncthreads();

    const float eta   = 0.2f / (1.0f + expf(-eta_raw[0]));
    const float alpha = 0.5f + 0.5f / (1.0f + expf(-alpha_raw[0]));
    if (lane < 32) {                          // lanes 0-15: chunk a, 16-31: chunk b
        const float* G = (lane < 16) ? Ga : Gb;
        float gtt = G[l15 * 17];
        float n   = fmaxf(sqrtf(gtt), 1e-6f);
        float inv = 1.0f / n;
        csh[lane] = eta * (1.0f - inv) * inv / alpha;
    }
    __syncthreads();

    if (lane < 32) {                          // column-parallel forward substitution x2
        const int j = l15;
        const float* G  = (lane < 16) ? Ga : Gb;
        const float* cp = (lane < 16) ? csh : csh + 16;
        float cr[16];
        #pragma unroll
        for (int k = 0; k < 16; ++k) cr[k] = cp[k];
        float Tcol[16];
        Tcol[0] = 0.f;
        #pragma unroll
        for (int t = 1; t < 16; ++t) {
            float acc = cr[j] * G[t * 16 + j];
            #pragma unroll
            for (int k = 1; k < 15; ++k)
                if (k < t) acc += cr[k] * G[t * 16 + k] * Tcol[k];
            Tcol[t] = (t > j) ? acc : 0.f;
        }
        float* Tsj = Ts[lane >> 4];
        #pragma unroll
        for (int t = 0; t < 16; ++t) Tsj[t * 16 + j] = Tcol[t];
    }
    __syncthreads();

    unsigned char* bp = blob + (size_t)(b * NP_ + p) * PBLOB_;
    const int idx = l15 * 16 + q * 4;
    *(bf16x4*)(bp + idx * 2)        = pk4(*(const f32x4*)(&Ts[0][idx]));
    *(bf16x4*)(bp + 512 + idx * 2)  = pk4(*(const f32x4*)(&Ts[1][idx]));
    *(bf16x4*)(bp + 1024 + idx * 2) = pk4(*(const f32x4*)(&Gxs[idx]));
    if (lane < 32) ((float*)(bp + 1536))[lane] = csh[lane];
}

// ---------------- main scan: one 512-thread block (8 waves) per (batch, rowblk).
// Pair-fused: per iteration both chunks' retrievals use the SAME master, reduced
// with ONE barrier; chunk b is corrected in-register via bb_b += Gx * eup_a.
// Master absorbs both rank-16 updates, then one *alpha^32 scale.
__global__ __launch_bounds__(512) void ldm_main(
    const float* __restrict__ x,
    const float* __restrict__ Minit,
    const float* __restrict__ alpha_raw,
    const unsigned char* __restrict__ blob,
    float* __restrict__ out)
{
    const int lane   = threadIdx.x & 63;
    const int w      = __builtin_amdgcn_readfirstlane(threadIdx.x >> 6); // 0..7
    const int batch  = blockIdx.x >> 4;
    const int rowblk = blockIdx.x & 15;
    const int l15    = lane & 15;
    const int q      = lane >> 4;
    const int kcol0  = w * 32 + q * 4;        // this wave's column base (+16 for frag 1)

    __shared__ f32x4 red[2][2][W_][64];       // [parity][chunk][wave][lane] = 32 KB

    const float alpha = 0.5f + 0.5f / (1.0f + expf(-alpha_raw[0]));
    const float a2 = alpha * alpha, a4 = a2 * a2, a8 = a4 * a4, a16 = a8 * a8;
    const float a32 = a16 * a16;
    const float aq = (q == 0) ? 1.f : (q == 1) ? a4 : (q == 2) ? a8 : a8 * a4;
    const f32x4 apowA = { aq, aq * alpha, aq * a2, aq * a2 * alpha };
    const f32x4 apowB = apowA * a16;

    // identity B-fragment for transpose MFMA
    const int s = l15 - (q << 2);
    bf16x4 IB;
    IB[0] = (s == 0) ? (short)0x3F80 : (short)0;
    IB[1] = (s == 1) ? (short)0x3F80 : (short)0;
    IB[2] = (s == 2) ? (short)0x3F80 : (short)0;
    IB[3] = (s == 3) ? (short)0x3F80 : (short)0;

    const int mrow = rowblk * 16 + l15;
    f32x4 master[2];
    master[0] = *(const f32x4*)(Minit + (size_t)mrow * D_ + kcol0);
    master[1] = *(const f32x4*)(Minit + (size_t)mrow * D_ + kcol0 + 16);

    const float* xb = x + (size_t)batch * S_ * D_;
    const unsigned char* bb0 = blob + (size_t)batch * NP_ * PBLOB_;
    float* outp = out + (size_t)batch * S_ * D_ + rowblk * 16 + l15;
    const int tfoff = (l15 * 16 + q * 4) * 2;

    struct PairBuf {
        f32x4  Xa[2], Xb[2];
        bf16x4 Ta, Tb, Gx;
        f32x4  ca, cb;
    };
    PairBuf Abuf, Bbuf;

    {   // preload pair 0
        const float* xp = xb + (size_t)l15 * D_ + kcol0;
        Abuf.Xa[0] = *(const f32x4*)(xp);
        Abuf.Xa[1] = *(const f32x4*)(xp + 16);
        Abuf.Xb[0] = *(const f32x4*)(xp + 16 * D_);
        Abuf.Xb[1] = *(const f32x4*)(xp + 16 * D_ + 16);
        Abuf.Ta = *(const bf16x4*)(bb0 + tfoff);
        Abuf.Tb = *(const bf16x4*)(bb0 + 512 + tfoff);
        Abuf.Gx = *(const bf16x4*)(bb0 + 1024 + tfoff);
        Abuf.ca = *(const f32x4*)(bb0 + 1536 + q * 16);
        Abuf.cb = *(const f32x4*)(bb0 + 1600 + q * 16);
    }

    auto body = [&](int p, PairBuf& cur, PairBuf& nxt) {
        const int par = p & 1;
        int px = p + 1; if (px > NP_ - 1) px = NP_ - 1;
        {   // prefetch pair p+1
            const float* xp = xb + ((size_t)px * 32 + l15) * D_ + kcol0;
            nxt.Xa[0] = *(const f32x4*)(xp);
            nxt.Xa[1] = *(const f32x4*)(xp + 16);
            nxt.Xb[0] = *(const f32x4*)(xp + 16 * D_);
            nxt.Xb[1] = *(const f32x4*)(xp + 16 * D_ + 16);
            const unsigned char* bp = bb0 + (size_t)px * PBLOB_;
            nxt.Ta = *(const bf16x4*)(bp + tfoff);
            nxt.Tb = *(const bf16x4*)(bp + 512 + tfoff);
            nxt.Gx = *(const bf16x4*)(bp + 1024 + tfoff);
            nxt.ca = *(const f32x4*)(bp + 1536 + q * 16);
            nxt.cb = *(const f32x4*)(bp + 1600 + q * 16);
        }
        bf16x4 m0 = pk4(master[0]), m1 = pk4(master[1]);   // once per PAIR now
        bf16x4 a0 = pk4(cur.Xa[0]), a1 = pk4(cur.Xa[1]);
        bf16x4 b0 = pk4(cur.Xb[0]), b1 = pk4(cur.Xb[1]);
        const f32x4 zz = {0,0,0,0};
        f32x4 acca = mfma_bf16(a0, m0, zz);
        acca = mfma_bf16(a1, m1, acca);
        f32x4 accb = mfma_bf16(b0, m0, zz);
        accb = mfma_bf16(b1, m1, accb);
        red[par][0][w][lane] = acca;
        red[par][1][w][lane] = accb;
        // X^T fragments (own cols) while other waves catch up
        f32x4 t0a = mfma_bf16(a0, IB, zz);
        f32x4 t1a = mfma_bf16(a1, IB, zz);
        f32x4 t0b = mfma_bf16(b0, IB, zz);
        f32x4 t1b = mfma_bf16(b1, IB, zz);
        __syncthreads();
        f32x4 r0 = red[par][0][0][lane], r1 = red[par][0][1][lane];
        f32x4 r2 = red[par][0][2][lane], r3 = red[par][0][3][lane];
        f32x4 r4 = red[par][0][4][lane], r5 = red[par][0][5][lane];
        f32x4 r6 = red[par][0][6][lane], r7 = red[par][0][7][lane];
        f32x4 bba = ((r0 + r1) + (r2 + r3)) + ((r4 + r5) + (r6 + r7));
        f32x4 s0 = red[par][1][0][lane], s1 = red[par][1][1][lane];
        f32x4 s2 = red[par][1][2][lane], s3 = red[par][1][3][lane];
        f32x4 s4 = red[par][1][4][lane], s5 = red[par][1][5][lane];
        f32x4 s6 = red[par][1][6][lane], s7 = red[par][1][7][lane];
        f32x4 bbb = ((s0 + s1) + (s2 + s3)) + ((s4 + s5) + (s6 + s7));

        // chunk a fixup: d_a = (I+T_a) * bb_a
        f32x4 da = mfma_bf16(cur.Ta, pk4(bba), bba);
        if (w == 0) {
            #pragma unroll
            for (int r = 0; r < 4; ++r)
                outp[(size_t)(p * 32 + q * 4 + r) * D_] = da[r] * apowA[r];
        }
        bf16x4 ea = pk4(da * cur.ca);
        // chunk b cross-correction: bb_b += Gx * E_a  (replaces 2nd barrier phase)
        f32x4 bbc = mfma_bf16(cur.Gx, ea, bbb);
        f32x4 db = mfma_bf16(cur.Tb, pk4(bbc), bbc);
        if (w == 1) {
            #pragma unroll
            for (int r = 0; r < 4; ++r)
                outp[(size_t)(p * 32 + 16 + q * 4 + r) * D_] = db[r] * apowB[r];
        }
        bf16x4 eb = pk4(db * cur.cb);
        // master += X_a^T E_a + X_b^T E_b, then *alpha^32
        master[0] = mfma_bf16(pk4(t0a), ea, master[0]);
        master[0] = mfma_bf16(pk4(t0b), eb, master[0]) * a32;
        master[1] = mfma_bf16(pk4(t1a), ea, master[1]);
        master[1] = mfma_bf16(pk4(t1b), eb, master[1]) * a32;
    };

    for (int p = 0; p < NP_; p += 2) {
        body(p,     Abuf, Bbuf);
        body(p + 1, Bbuf, Abuf);
    }

    // M_final -> second output region [B, D, D]
    float* Mout = out + (size_t)B_ * S_ * D_
                + ((size_t)batch * D_ + mrow) * D_;
    *(f32x4*)(Mout + kcol0)      = master[0];
    *(f32x4*)(Mout + kcol0 + 16) = master[1];
}

extern "C" void kernel_launch(void* const* d_in, const int* in_sizes, int n_in,
                              void* d_out, int out_size, void* d_ws, size_t ws_size,
                              hipStream_t stream) {
    const float* x         = (const float*)d_in[0];
    const float* Minit     = (const float*)d_in[1];
    const float* eta_raw   = (const float*)d_in[2];
    const float* alpha_raw = (const float*)d_in[3];
    float* out = (float*)d_out;
    unsigned char* blob = (unsigned char*)d_ws;   // B_*NP_*1664 = 3.4 MB

    hipLaunchKernelGGL(ldm_prep, dim3(B_ * NP_), dim3(64), 0, stream,
                       x, eta_raw, alpha_raw, blob);
    hipLaunchKernelGGL(ldm_main, dim3(B_ * 16), dim3(512), 0, stream,
                       x, Minit, alpha_raw, blob, out);
}